// Round 3
// baseline (7467.583 us; speedup 1.0000x reference)
//
#include <hip/hip_runtime.h>
#include <cstddef>
#include <math.h>

#define SEQ   256
#define BATCH 2048
#define FD    5
#define HD    64
#define KAUX  8
#define NCOL  1280   // 256 gm cols + 1024 ga cols
#define ROWS  8
#define NTHR  256

// Accurate libm-based activations (match jax/np fp32 to ~1-2 ulp).
__device__ __forceinline__ float sigm(float x) { return 1.0f / (1.0f + expf(-x)); }
__device__ __forceinline__ float tanh_f(float x) { return tanhf(x); }

__device__ __forceinline__ float wave_sum(float v) {
#pragma unroll
    for (int m = 1; m < 64; m <<= 1) v += __shfl_xor(v, m);
    return v;
}

__global__ __launch_bounds__(NTHR, 1)
void minet_fused(const float* __restrict__ Y,
                 const float* __restrict__ x1, const float* __restrict__ x2,
                 const float* __restrict__ x3, const float* __restrict__ x4,
                 const float* __restrict__ x5, const float* __restrict__ x6,
                 const float* __restrict__ x7, const float* __restrict__ x8,
                 const float* __restrict__ W_main, const float* __restrict__ U_main,
                 const float* __restrict__ b_main, const float* __restrict__ W_aux,
                 const float* __restrict__ U_aux,  const float* __restrict__ b_aux,
                 const float* __restrict__ W_att,  const float* __restrict__ b_att,
                 const float* __restrict__ W_ih,   const float* __restrict__ W_hh,
                 const float* __restrict__ b_ih,   const float* __restrict__ b_hh,
                 const float* __restrict__ lin_W,  const float* __restrict__ lin_b,
                 float* __restrict__ out)
{
    __shared__ __align__(16) float h1[ROWS][HD];
    __shared__ __align__(16) float c1[ROWS][HD];
    __shared__ __align__(16) float h2[ROWS][HD];
    __shared__ __align__(16) float outb[ROWS][NCOL];       // 40 KB
    __shared__ __align__(16) float outg[2][ROWS][256];     // 16 KB (ih-part, hh-part)
    __shared__ __align__(16) float inb[ROWS][9][8];        // slot 0 = Y, 1..8 = x1..x8; f padded to 8
    __shared__ __align__(16) float WaT[HD * HD];           // 16 KB: WaT[g*64+h] = W_att[h,g]

    const int tid  = threadIdx.x;
    const int lane = tid & 63;
    const int wid  = tid >> 6;          // 4 waves
    const int b0   = blockIdx.x * ROWS; // batch base

    // ---------- one-time setup ----------
    // Stage W_att transposed: WaT[g][h] = W_att[h][g]
    for (int i = tid; i < HD * HD; i += NTHR) {
        int g = i >> 6, h = i & 63;
        WaT[i] = W_att[h * 64 + g];
    }

    // P3 column ownership: cols c_j = tid + 256*j, j=0..4  (covers 0..1279)
    const float* uptr[5];
    float wf[5][5];
    float bias[5];
    int   inoff[5];                      // LDS float-offset of input slot row-start (within a row)
#pragma unroll
    for (int j = 0; j < 5; ++j) {
        if (j == 0) {
            uptr[0] = U_main + tid;                       // stride 256 per h
#pragma unroll
            for (int f = 0; f < FD; ++f) wf[0][f] = W_main[f * 256 + tid];
            bias[0]  = b_main[tid];
            inoff[0] = 0;                                  // slot 0
        } else {
            int c  = tid + 256 * j - 256;                  // 0..1023
            int kk = c >> 7, gg = c & 127;
            uptr[j] = U_aux + (size_t)kk * 64 * 128 + gg;  // stride 128 per h
#pragma unroll
            for (int f = 0; f < FD; ++f) wf[j][f] = W_aux[(kk * 5 + f) * 128 + gg];
            bias[j]  = b_aux[kk * 128 + gg];
            inoff[j] = (1 + kk) * 8;                       // slot 1+kk
        }
    }

    // LSTM2 weights: threads 0..127 own W_ih cols {cc, cc+128}; 128..255 own W_hh cols
    const float* wsrc = (tid < 128) ? W_ih : W_hh;
    const int cc = tid & 127;
    float4 w2v[2][16];
#pragma unroll
    for (int j2 = 0; j2 < 2; ++j2)
#pragma unroll
        for (int hb = 0; hb < 16; ++hb)
            w2v[j2][hb] = *(const float4*)(wsrc + (size_t)(cc + 128 * j2) * 64 + hb * 4);
    float bias2[2];
#pragma unroll
    for (int j2 = 0; j2 < 2; ++j2)
        bias2[j2] = (tid < 128) ? (b_ih[cc + 128 * j2] + b_hh[cc + 128 * j2]) : 0.0f;

    const float linw = lin_W[lane];
    const float linb = lin_b[0];
    const float batt = b_att[0];

    // zero states + inb padding
    for (int i = tid; i < ROWS * HD; i += NTHR) {
        (&h1[0][0])[i] = 0.0f; (&c1[0][0])[i] = 0.0f; (&h2[0][0])[i] = 0.0f;
    }
    for (int i = tid; i < ROWS * 9 * 8; i += NTHR) (&inb[0][0][0])[i] = 0.0f;
    float c2r[2] = {0.0f, 0.0f};

    // input prefetch lanes: 360 values = 8 rows x 9 slots x 5 feats
    bool  pon[2]; const float* psrc[2]; int pofs[2]; float pf[2];
#pragma unroll
    for (int q = 0; q < 2; ++q) {
        int idx = tid + 256 * q;
        pon[q] = idx < 360;
        int r = idx / 45, rem = idx % 45;
        int s = rem / 5, f = rem % 5;
        const float* base = Y;
        if (s == 1) base = x1; else if (s == 2) base = x2; else if (s == 3) base = x3;
        else if (s == 4) base = x4; else if (s == 5) base = x5; else if (s == 6) base = x6;
        else if (s == 7) base = x7; else if (s == 8) base = x8;
        psrc[q] = base + (size_t)(b0 + r) * FD + f;
        pofs[q] = (r * 9 + s) * 8 + f;
        pf[q] = 0.0f;
        if (pon[q]) pf[q] = psrc[q][0];    // t = 0
    }

    const int r0 = wid * 2;   // this wave's two rows

    for (int t = 0; t < SEQ; ++t) {
        // ---- P1: publish staged inputs for step t
#pragma unroll
        for (int q = 0; q < 2; ++q)
            if (pon[q]) (&inb[0][0][0])[pofs[q]] = pf[q];
        __syncthreads();   // BAR_A: inb ready; prev-step h1/c1/h2 visible

        // prefetch t+1 (latency hidden under compute below)
        if (t + 1 < SEQ) {
#pragma unroll
            for (int q = 0; q < 2; ++q)
                if (pon[q]) pf[q] = psrc[q][(size_t)(t + 1) * BATCH * FD];
        }

        // ---- P3: 1280-col dot  out[r][c] = bias + in·wf + h1[r]·Ucol
        float acc[5][ROWS];
#pragma unroll
        for (int j = 0; j < 5; ++j) {
#pragma unroll
            for (int r = 0; r < ROWS; ++r) {
                const float* ip = &inb[r][0][0] + inoff[j];
                float4 ia = *(const float4*)ip;
                float  i4 = ip[4];
                acc[j][r] = bias[j] + ia.x * wf[j][0] + ia.y * wf[j][1] + ia.z * wf[j][2]
                                    + ia.w * wf[j][3] + i4 * wf[j][4];
            }
        }
        {
            const float* up[5];
#pragma unroll
            for (int j = 0; j < 5; ++j) up[j] = uptr[j];
#pragma unroll 2
            for (int hb = 0; hb < 16; ++hb) {
                float s4a[ROWS][4];
#pragma unroll
                for (int r = 0; r < ROWS; ++r) {
                    float4 f4 = *(const float4*)&h1[r][hb * 4];
                    s4a[r][0] = f4.x; s4a[r][1] = f4.y; s4a[r][2] = f4.z; s4a[r][3] = f4.w;
                }
#pragma unroll
                for (int hi = 0; hi < 4; ++hi) {
                    float w[5];
#pragma unroll
                    for (int j = 0; j < 5; ++j)
                        w[j] = up[j][(size_t)hi * (j == 0 ? 256 : 128)];
#pragma unroll
                    for (int j = 0; j < 5; ++j)
#pragma unroll
                        for (int r = 0; r < ROWS; ++r)
                            acc[j][r] = fmaf(s4a[r][hi], w[j], acc[j][r]);
                }
#pragma unroll
                for (int j = 0; j < 5; ++j) up[j] += 4 * (j == 0 ? 256 : 128);
            }
        }
#pragma unroll
        for (int j = 0; j < 5; ++j)
#pragma unroll
            for (int r = 0; r < ROWS; ++r)
                outb[r][tid + 256 * j] = acc[j][r];

        // ---- P4b: v[h=lane] = sum_g W_att[h,g] * c_prev[r][g]   (this wave's 2 rows)
        // c broadcast via shuffle; W_att^T streamed from LDS (conflict-free: lane-consecutive)
        float v0 = 0.0f, v1 = 0.0f;
        {
            float cr0 = c1[r0][lane];
            float cr1 = c1[r0 + 1][lane];
#pragma unroll
            for (int g = 0; g < 64; ++g) {
                float w = WaT[g * 64 + lane];
                v0 = fmaf(__shfl(cr0, g), w, v0);
                v1 = fmaf(__shfl(cr1, g), w, v1);
            }
        }
        __syncthreads();   // BAR_B: outb ready

        // ---- P5: gates + attention softmax + MI state update (wave w -> rows 2w,2w+1)
#pragma unroll
        for (int rr = 0; rr < 2; ++rr) {
            const int r = r0 + rr;
            const float vv = rr ? v1 : v0;
            float gi = outb[r][lane],       gf = outb[r][64 + lane];
            float go = outb[r][128 + lane], gc = outb[r][192 + lane];
            float ii = sigm(gi), ff = sigm(gf), oo = sigm(go), cm = tanh_f(gc);
            float l[9];
            l[0] = ii * cm;
#pragma unroll
            for (int k = 1; k <= 8; ++k) {
                float a_ = outb[r][256 + (k - 1) * 128 + lane];
                float b_ = outb[r][256 + (k - 1) * 128 + 64 + lane];
                l[k] = sigm(a_) * tanh_f(b_);
            }
            float u[9]; float umax = -1e30f;
#pragma unroll
            for (int k = 0; k < 9; ++k) {
                float p = wave_sum(l[k] * vv);
                u[k] = tanh_f(p + batt);
                umax = fmaxf(umax, u[k]);
            }
            float den = 0.0f, Lh = 0.0f;
#pragma unroll
            for (int k = 0; k < 9; ++k) {
                float e = expf(u[k] - umax);
                den += e;
                Lh = fmaf(e, l[k], Lh);
            }
            Lh /= den;
            float cp = c1[r][lane];
            float cn = fmaf(ff, cp, Lh);
            float hn = oo * tanh_f(cn);
            c1[r][lane] = cn;
            h1[r][lane] = hn;
        }
        __syncthreads();   // BAR_C: h1 (hs[t]) ready

        // ---- P6: LSTM2 pre-activations. threads<128: ih-part (state h1); else hh-part (state h2)
        {
            float acc2[2][ROWS];
#pragma unroll
            for (int j2 = 0; j2 < 2; ++j2)
#pragma unroll
                for (int r = 0; r < ROWS; ++r) acc2[j2][r] = bias2[j2];
            const float(*SS)[HD] = (tid < 128) ? h1 : h2;
#pragma unroll
            for (int hb = 0; hb < 16; ++hb) {
                float s4a[ROWS][4];
#pragma unroll
                for (int r = 0; r < ROWS; ++r) {
                    float4 f4 = *(const float4*)&SS[r][hb * 4];
                    s4a[r][0] = f4.x; s4a[r][1] = f4.y; s4a[r][2] = f4.z; s4a[r][3] = f4.w;
                }
#pragma unroll
                for (int j2 = 0; j2 < 2; ++j2) {
                    float4 w4 = w2v[j2][hb];
#pragma unroll
                    for (int r = 0; r < ROWS; ++r)
                        acc2[j2][r] = fmaf(s4a[r][0], w4.x,
                                      fmaf(s4a[r][1], w4.y,
                                      fmaf(s4a[r][2], w4.z,
                                      fmaf(s4a[r][3], w4.w, acc2[j2][r]))));
                }
            }
            const int part = (tid < 128) ? 0 : 1;
#pragma unroll
            for (int j2 = 0; j2 < 2; ++j2)
#pragma unroll
                for (int r = 0; r < ROWS; ++r)
                    outg[part][r][cc + 128 * j2] = acc2[j2][r];
        }
        __syncthreads();   // BAR_D: outg ready

        // ---- P7: LSTM2 gates (torch order i,f,g,o) + output projection
#pragma unroll
        for (int rr = 0; rr < 2; ++rr) {
            const int r = r0 + rr;
            float g0 = outg[0][r][lane]       + outg[1][r][lane];
            float g1 = outg[0][r][64 + lane]  + outg[1][r][64 + lane];
            float g2 = outg[0][r][128 + lane] + outg[1][r][128 + lane];
            float g3 = outg[0][r][192 + lane] + outg[1][r][192 + lane];
            float i2 = sigm(g0), f2 = sigm(g1), gg = tanh_f(g2), o2 = sigm(g3);
            float cn = fmaf(f2, c2r[rr], i2 * gg);
            c2r[rr] = cn;
            float hn = o2 * tanh_f(cn);
            h2[r][lane] = hn;
            float e = wave_sum(fmaxf(hn, 0.0f) * linw);
            if (lane == 0) out[(size_t)t * BATCH + b0 + r] = e + linb;
        }
        // no barrier needed here: next-iteration BAR_A separates h2 writes from P6 reads
    }
}

extern "C" void kernel_launch(void* const* d_in, const int* in_sizes, int n_in,
                              void* d_out, int out_size, void* d_ws, size_t ws_size,
                              hipStream_t stream) {
    const float* Y      = (const float*)d_in[0];
    const float* x1     = (const float*)d_in[1];
    const float* x2     = (const float*)d_in[2];
    const float* x3     = (const float*)d_in[3];
    const float* x4     = (const float*)d_in[4];
    const float* x5     = (const float*)d_in[5];
    const float* x6     = (const float*)d_in[6];
    const float* x7     = (const float*)d_in[7];
    const float* x8     = (const float*)d_in[8];
    const float* W_main = (const float*)d_in[9];
    const float* U_main = (const float*)d_in[10];
    const float* b_main = (const float*)d_in[11];
    const float* W_aux  = (const float*)d_in[12];
    const float* U_aux  = (const float*)d_in[13];
    const float* b_aux  = (const float*)d_in[14];
    const float* W_att  = (const float*)d_in[15];
    const float* b_att  = (const float*)d_in[16];
    const float* W_ih   = (const float*)d_in[17];
    const float* W_hh   = (const float*)d_in[18];
    const float* b_ih   = (const float*)d_in[19];
    const float* b_hh   = (const float*)d_in[20];
    const float* lin_W  = (const float*)d_in[21];
    const float* lin_b  = (const float*)d_in[22];
    float* out = (float*)d_out;

    dim3 grid(BATCH / ROWS);   // 256 blocks, 8 batch rows each
    dim3 block(NTHR);
    minet_fused<<<grid, block, 0, stream>>>(Y, x1, x2, x3, x4, x5, x6, x7, x8,
                                            W_main, U_main, b_main, W_aux, U_aux, b_aux,
                                            W_att, b_att, W_ih, W_hh, b_ih, b_hh,
                                            lin_W, lin_b, out);
}